// Round 8
// baseline (509.054 us; speedup 1.0000x reference)
//
#include <hip/hip_runtime.h>
#include <hip/hip_bf16.h>

// Problem constants
#define NNEUR 8192
#define NCONV 64
#define LYC   36
#define LXC   36
#define BATCH 256
#define KRAW  1296   // 36*36
#define KPAD  1344   // 21*64
#define KITER 21     // KPAD/64
#define MROWS 16384  // BATCH*NCONV
#define BM 256
#define BN 128
#define BK 64
// Staged-chunk geometry: one chunk = 16 B = 8 halfs.
#define ACH_PER_IT 2048   // BM*BK/8
#define BCH_PER_IT 1024   // BN*BK/8
#define A_TILE_H   (KITER * ACH_PER_IT * 8)  // halfs per m-tile = 344064
#define B_TILE_H   (KITER * BCH_PER_IT * 8)  // halfs per n-tile = 172032

typedef __attribute__((ext_vector_type(8))) _Float16 half8;
typedef __attribute__((ext_vector_type(4))) float f32x4;
typedef __attribute__((ext_vector_type(16))) float f32x16;

__device__ __forceinline__ void async_copy16(const void* g, void* l) {
  __builtin_amdgcn_global_load_lds(
      (const __attribute__((address_space(1))) void*)g,
      (__attribute__((address_space(3))) void*)l, 16, 0, 0);
}

// Prep: CHUNK-MAJOR images (round-5 prep, verified bit-correct with the
// chunk-major GEMM). Per (tile, it) the image holds 16B chunks at
// position p: A: p = c*256 + r (c = k-chunk 0..7, r = row 0..255);
//             B: p = c*128 + r.
// A is staged linearly into LDS by the GEMM (ends up chunk-major ->
// fragment reads 512B contiguous per half-wave, conflict-free). B is read
// DIRECTLY into VGPRs by the GEMM at per-fragment addresses (cc*128+r)*16B
// -- 512B contiguous per (nb,hh) lane-group, coalesced, L2-resident.
// grid: x = 0..167 -> A (it = x>>3, i = x&7, mtile = y);
//       x = 168..251 -> B (x'=x-168, it = x'>>2, i4 = x'&3, ntile = y).
__global__ __launch_bounds__(256) void prep_kernel(
    const float* __restrict__ conv, const float* __restrict__ Wy,
    const float* __restrict__ Wx, _Float16* __restrict__ A,
    _Float16* __restrict__ B) {
  const int t = threadIdx.x;
  const int bx = blockIdx.x;
  const int tile = blockIdx.y;
  const int c = t & 7;  // chunk index within the BK=64 row
  half8 h;
  if (bx < 168) {  // A part: conv -> f16
    const int it = bx >> 3, i = bx & 7;
    const int r = (t >> 3) + 32 * i;                 // row in tile, 0..255
    const int k0 = it * 64 + c * 8;
    const int grow = tile * BM + r;
    if (k0 < KRAW) {  // chunk fully valid (KRAW is a multiple of 8)
      const float* s = conv + (size_t)grow * KRAW + k0;
#pragma unroll
      for (int e = 0; e < 8; e++) h[e] = (_Float16)s[e];
    } else {
#pragma unroll
      for (int e = 0; e < 8; e++) h[e] = (_Float16)0.f;
    }
    *(half8*)(A + (size_t)tile * A_TILE_H + (size_t)it * (ACH_PER_IT * 8) +
              ((size_t)c * 256 + r) * 8) = h;
  } else {  // B part: Wy*Wx*256 -> f16
    const int bxp = bx - 168;                        // 0..83
    const int it = bxp >> 2, i4 = bxp & 3;           // it 0..20
    const int r = (t >> 3) + 32 * i4;                // row in tile, 0..127
    const int k0 = it * 64 + c * 8;
    const int n = tile * BN + r;
    if (k0 < KRAW) {  // chunk fully valid
      const float* wyn = Wy + n * LYC;
      const float* wxn = Wx + n * LXC;
      int y = k0 / LXC;
      int x = k0 - y * LXC;
#pragma unroll
      for (int e = 0; e < 8; e++) {
        h[e] = (_Float16)(wyn[y] * wxn[x] * 256.f);
        if (++x == LXC) { x = 0; ++y; }
      }
    } else {
#pragma unroll
      for (int e = 0; e < 8; e++) h[e] = (_Float16)0.f;
    }
    *(half8*)(B + (size_t)tile * B_TILE_H + (size_t)it * (BCH_PER_IT * 8) +
              ((size_t)c * 128 + r) * 8) = h;
  }
}

// Fused GEMM v6: A-dbuf-LDS + B-direct-to-register, counted vmcnt.
// Block tile 256(M)x128(N), BK=64, 4 waves (2x2), wave tile 128x64 =
// [4 mb][2 nb] of 32x32x16 f16 MFMA (acc 8 x f32x16 = 128 AGPR).
// LDS = A only, 2 x 32 KB double buffer (-> 2 blocks/CU, same as r0's
// register-limited occupancy). B fragments live in 8 half8 regs (bq),
// reloaded for tile t+1 AFTER their last use in tile t (lookahead =
// trailing barrier + stage + wait ~400 cy; B slice 2.75 MB L2-resident).
// Per iter: stage A(t+1) -> vmcnt(16) (in-order queue A(t)(8),B(t)(8),
// A(t+1)(8): <=16 retires A(t), issued one FULL iteration earlier ->
// drain ~0; never vmcnt(0) until the tail) -> barrier -> 4 ks phases
// (compiler inserts the counted B wait) -> reload bq -> barrier.
// Exactly 2 barriers/iter, same tile/occupancy as the proven r0 kernel --
// only the per-iteration latency drain is removed.
__global__ __launch_bounds__(256, 2) void gemm_fused_kernel(
    const _Float16* __restrict__ A, const _Float16* __restrict__ B,
    const float* __restrict__ Wc, const float* __restrict__ bias,
    float* __restrict__ out) {
  __shared__ _Float16 As[2][BM * BK];  // 2 x 32 KB, chunk-major c*2048+r*8

  // XCD swizzle: xcd = bid&7; within an XCD, n varies fastest so the 8
  // blocks sharing one A-tile are consecutive; B panel (8 n-tiles, 2.75 MB)
  // stays L2-resident per XCD.
  const int bid = blockIdx.x;      // 0..4095
  const int l = bid >> 3;          // 0..511
  const int ntile = (bid & 7) * 8 + (l & 7);  // 0..63
  const int mtile = l >> 3;                   // 0..63
  const int tileN = ntile * BN;

  const int t = threadIdx.x;
  const int lane = t & 63;
  const int wave = t >> 6;
  const int wm = wave >> 1, wn = wave & 1;  // 2x2 waves; wave tile 128x64
  const int r32 = lane & 31, hh = lane >> 5;

  f32x16 acc[4][2] = {};  // [mb][nb], mb: 4x32 rows, nb: 2x32 cols

  const _Float16* pA = A + (size_t)mtile * A_TILE_H;
  const _Float16* pB = B + (size_t)ntile * B_TILE_H;

  auto stage = [&](int b, int it) {
    const _Float16* sA = pA + (size_t)it * (ACH_PER_IT * 8) + t * 8;
    _Float16* lA = &As[b][t * 8];
#pragma unroll
    for (int i = 0; i < 8; i++) async_copy16(sA + i * 2048, lA + i * 2048);
  };

  half8 bq[8];  // [ks*2+nb] B fragments for the current K-tile
  auto loadB = [&](int it) {
    const _Float16* base = pB + (size_t)it * (BCH_PER_IT * 8);
#pragma unroll
    for (int ks = 0; ks < 4; ks++)
#pragma unroll
      for (int nb = 0; nb < 2; nb++) {
        const int r = wn * 64 + nb * 32 + r32;
        bq[ks * 2 + nb] =
            *(const half8*)(base + ((size_t)(2 * ks + hh) * 128 + r) * 8);
      }
  };

  stage(0, 0);
  asm volatile("" ::: "memory");  // pin queue order: A(0) before B(0)
  loadB(0);

#pragma unroll 1
  for (int it = 0; it < KITER; ++it) {
    const int cbuf = it & 1;
    if (it + 1 < KITER) {
      // As[cbuf^1]'s readers finished at iter (it-1)'s trailing barrier.
      stage(cbuf ^ 1, it + 1);
      // Queue: A(it)(8), B(it)(8), A(it+1)(8) -> <=16 retires A(it),
      // which was issued one full compute-iteration ago (~no stall).
      asm volatile("s_waitcnt vmcnt(16)" ::: "memory");
    } else {
      // Tail: queue = A(20)(8), B(20)(8) -> <=8 retires A(20).
      asm volatile("s_waitcnt vmcnt(8)" ::: "memory");
    }
    __builtin_amdgcn_s_barrier();  // As[cbuf] visible to all waves
#pragma unroll
    for (int ks = 0; ks < 4; ks++) {
      const int cc = 2 * ks + hh;  // source chunk for this k-substep
      half8 af[4];
#pragma unroll
      for (int mb = 0; mb < 4; mb++) {
        const int r = wm * 128 + mb * 32 + r32;
        af[mb] = *(const half8*)(&As[cbuf][cc * 2048 + r * 8]);
      }
#pragma unroll
      for (int mb = 0; mb < 4; mb++)
#pragma unroll
        for (int nb = 0; nb < 2; nb++)
          acc[mb][nb] = __builtin_amdgcn_mfma_f32_32x32x16_f16(
              af[mb], bq[ks * 2 + nb], acc[mb][nb], 0, 0, 0);
    }
    if (it + 1 < KITER) {
      // Reload bq for tile it+1 after its last use (reg WAR keeps order);
      // fence pins these loads after stage(it+1) in the vmcnt queue.
      asm volatile("" ::: "memory");
      loadB(it + 1);
    }
    __builtin_amdgcn_s_barrier();  // all reads of As[cbuf] done
  }

  // Epilogue. C/D layout (32x32): col = lane&31, row = (reg&3)+8*(reg>>2)+4*hh.
  // Wave rows = 128 = 2 images x 64 channels; mb pairs (0,1)->img0, (2,3)->img1;
  // channel = (mb&1)*32 + row. (Verified rounds 0-7.)
  const int ibase = mtile * 4 + wm * 2;
  float v[2][2];  // [img][nb]
#pragma unroll
  for (int nb = 0; nb < 2; nb++) {
    const int n_g = tileN + wn * 64 + nb * 32 + r32;
    const float* wc = Wc + (size_t)n_g * NCONV;
    f32x4 w[2][4];
#pragma unroll
    for (int hf = 0; hf < 2; hf++)
#pragma unroll
      for (int g = 0; g < 4; g++)
        w[hf][g] = *(const f32x4*)(wc + hf * 32 + hh * 4 + g * 8);
#pragma unroll
    for (int img = 0; img < 2; img++) {
      float p = 0.f;
#pragma unroll
      for (int hf = 0; hf < 2; hf++)
#pragma unroll
        for (int g = 0; g < 4; g++)
#pragma unroll
          for (int q = 0; q < 4; q++)
            p += acc[img * 2 + hf][nb][g * 4 + q] * w[hf][g][q];
      p += __shfl_xor(p, 32);
      v[img][nb] = p;
    }
  }
  // Each lane writes image hh (its half), both nb; values identical per half.
  const int img = ibase + hh;
#pragma unroll
  for (int nb = 0; nb < 2; nb++) {
    const int n_out = tileN + wn * 64 + nb * 32 + r32;
    float z = v[hh][nb] * 0.00390625f + bias[n_out];  // undo x256 scaling
    z = z > 0.f ? z : (__expf(z) - 1.f);
    out[(size_t)img * NNEUR + n_out] = z;
  }
}

extern "C" void kernel_launch(void* const* d_in, const int* in_sizes, int n_in,
                              void* d_out, int out_size, void* d_ws,
                              size_t ws_size, hipStream_t stream) {
  const float* conv = (const float*)d_in[0];
  const float* Wc = (const float*)d_in[1];
  const float* Wy = (const float*)d_in[2];
  const float* Wx = (const float*)d_in[3];
  const float* bias = (const float*)d_in[4];
  float* out = (float*)d_out;

  _Float16* Abuf = (_Float16*)d_ws;                                      // 44.0 MB
  _Float16* Bbuf = (_Float16*)((char*)d_ws + (size_t)MROWS * KPAD * 2);  // 22.0 MB

  prep_kernel<<<dim3(252, 64), 256, 0, stream>>>(conv, Wy, Wx, Abuf, Bbuf);
  gemm_fused_kernel<<<4096, 256, 0, stream>>>(Abuf, Bbuf, Wc, bias, out);
}